// Round 7
// baseline (626.510 us; speedup 1.0000x reference)
//
#include <hip/hip_runtime.h>

#define LBL 64
#define TT 1024
#define BB 256
#define BOS 62
#define EOS 63
#define NEGV -10000.0f
#define RS 32          // fv/pv ring slots = 4 windows of 8
#define NW (TT / 8)    // 128 eight-step windows

__device__ __forceinline__ float rl_f(float v, int l) {
    return __uint_as_float(__builtin_amdgcn_readlane(__float_as_uint(v), l));
}
__device__ __forceinline__ int acq(int* p) {
    return __hip_atomic_load(p, __ATOMIC_ACQUIRE, __HIP_MEMORY_SCOPE_WORKGROUP);
}
__device__ __forceinline__ void rel(int* p, int v) {
    __hip_atomic_store(p, v, __ATOMIC_RELEASE, __HIP_MEMORY_SCOPE_WORKGROUP);
}

// Barrier-free producer/consumer pipeline, one sentence per block (4 waves):
//   wave 0: value-only fv recurrence -> fv ring   (the serial critical path)
//   waves 1,2: argmax over prev-halves, lag 1 window (8 steps)
//   wave 3: combine halves -> bp, lag 2 windows
// Sync = LDS acquire/release tickets; NO s_barrier in the loop -> no
// vmcnt/lgkmcnt drains on the critical path.
__global__ __launch_bounds__(256, 1) void viterbi_kernel(
    const float* __restrict__ X, const float* __restrict__ trans,
    float* __restrict__ out)
{
    __shared__ float fvring[RS][LBL];            // 8 KiB fv history ring
    __shared__ float pv[2][RS][LBL];             // 16 KiB partial maxima
    __shared__ unsigned char pi8[2][RS][LBL];    // 4 KiB partial argmax (global p)
    __shared__ unsigned char bp[TT][LBL];        // 64 KiB backpointers
    __shared__ unsigned char path_s[TT];
    __shared__ int tk_prod, tk_cons0, tk_cons1, tk_comb;

    const int tid  = threadIdx.x;
    const int lane = tid & 63;                   // next-label n
    const int wv   = __builtin_amdgcn_readfirstlane(tid >> 6);
    const int b    = blockIdx.x;
    const float* Xb = X + (size_t)b * TT * LBL;

    float fvv = (lane == BOS) ? 0.0f : NEGV;     // fv_{-1}
    if (wv == 0) fvring[0][lane] = fvv;          // slot 0 = fv_{-1}
    if (tid == 0) { tk_prod = 0; tk_cons0 = 0; tk_cons1 = 0; tk_comb = 0; }
    __syncthreads();                             // publish init (only loop-external barrier)

    if (wv == 0) {
        // ---------------- producer: value-only fv recurrence ----------------
        float tc[LBL];
#pragma unroll
        for (int p = 0; p < LBL; ++p) tc[p] = trans[p * LBL + lane];

        float eA[8], eB[8];
#pragma unroll
        for (int j = 0; j < 8; ++j) eA[j] = Xb[j * LBL + lane];

        auto DOW = [&](float (&cur)[8], float (&nxt)[8], int W) {
            // issue next window's emissions (complete during this window's ~3k cyc)
#pragma unroll
            for (int j = 0; j < 8; ++j) {
                int st = 8 * (W + 1) + j; if (st > TT - 1) st = TT - 1;
                nxt[j] = Xb[(size_t)st * LBL + lane];
            }
#pragma unroll
            for (int j = 0; j < 8; ++j) {
                float mm[16];
#pragma unroll
                for (int g = 0; g < 16; ++g) {
                    float a0 = rl_f(fvv, 4*g+0) + tc[4*g+0];
                    float a1 = rl_f(fvv, 4*g+1) + tc[4*g+1];
                    float a2 = rl_f(fvv, 4*g+2) + tc[4*g+2];
                    float a3 = rl_f(fvv, 4*g+3) + tc[4*g+3];
                    mm[g] = fmaxf(fmaxf(a0, a1), fmaxf(a2, a3));  // max3-fusable
                }
#pragma unroll
                for (int st = 8; st >= 1; st >>= 1)
#pragma unroll
                    for (int k = 0; k < st; ++k)
                        mm[k] = fmaxf(mm[2*k], mm[2*k+1]);
                fvv = mm[0] + cur[j];                        // exact f32 adds
                fvring[(8*W + j + 1) & (RS-1)][lane] = fvv;  // publish fv_t
            }
        };

        for (int W = 0; W < NW; ++W) {
            if (W >= 3) {   // ring back-pressure (normally satisfied already)
                while (acq(&tk_cons0) < W-2 || acq(&tk_cons1) < W-2)
                    __builtin_amdgcn_s_sleep(1);
            }
            if ((W & 1) == 0) DOW(eA, eB, W);
            else              DOW(eB, eA, W);
            rel(&tk_prod, W + 1);
        }
    } else if (wv <= 2) {
        // ---------- consumers: argmax over 32 prevs, lag 1 window ----------
        const int ww = wv - 1, pbase = ww * 32;
        float tcr[32];
#pragma unroll
        for (int i = 0; i < 32; ++i) tcr[i] = trans[(pbase + i) * LBL + lane];

        for (int W = 1; W <= NW; ++W) {
            while (acq(&tk_prod) < W) __builtin_amdgcn_s_sleep(1);
            if (W >= 5) {   // pv-ring back-pressure vs combiner
                while (acq(&tk_comb) < W-4) __builtin_amdgcn_s_sleep(1);
            }
            const int tb = 8 * (W - 1);
#pragma unroll
            for (int j = 0; j < 8; ++j) {
                const int t = tb + j, slot = t & (RS - 1);
                const float4* fr = (const float4*)&fvring[slot][pbase];
                float vgv[8]; int vgi[8];
#pragma unroll
                for (int g = 0; g < 8; ++g) {
                    float4 f = fr[g];   // broadcast b128 (same addr all lanes)
                    float a0 = f.x + tcr[4*g+0];
                    float a1 = f.y + tcr[4*g+1];
                    float a2 = f.z + tcr[4*g+2];
                    float a3 = f.w + tcr[4*g+3];
                    // strict '>' + ascending p = first-occurrence (np.argmax)
                    bool c01 = a1 > a0; float v01 = c01 ? a1 : a0;
                    int  i01 = 4*g + (c01 ? 1 : 0);
                    bool c23 = a3 > a2; float v23 = c23 ? a3 : a2;
                    int  i23 = 4*g + 2 + (c23 ? 1 : 0);
                    bool cg  = v23 > v01;
                    vgv[g] = cg ? v23 : v01;
                    vgi[g] = cg ? i23 : i01;
                }
#pragma unroll
                for (int st = 4; st >= 1; st >>= 1)
#pragma unroll
                    for (int k = 0; k < st; ++k) {
                        bool c = vgv[2*k+1] > vgv[2*k];
                        vgv[k] = c ? vgv[2*k+1] : vgv[2*k];
                        vgi[k] = c ? vgi[2*k+1] : vgi[2*k];
                    }
                pv[ww][slot][lane]  = vgv[0];
                pi8[ww][slot][lane] = (unsigned char)(pbase + vgi[0]);
            }
            if (ww == 0) rel(&tk_cons0, W); else rel(&tk_cons1, W);
        }
    } else {
        // ---------- combiner: merge halves -> bp, lag 2 windows ----------
        for (int W = 2; W <= NW + 1; ++W) {
            while (acq(&tk_cons0) < W-1 || acq(&tk_cons1) < W-1)
                __builtin_amdgcn_s_sleep(1);
            const int tb = 8 * (W - 2);
#pragma unroll
            for (int j = 0; j < 8; ++j) {
                const int t = tb + j, slot = t & (RS - 1);
                float v1 = pv[0][slot][lane];
                float v2 = pv[1][slot][lane];
                // lower half wins ties (strict '>') = first-occurrence
                bp[t][lane] = (v2 > v1) ? pi8[1][slot][lane]
                                        : pi8[0][slot][lane];
            }
            rel(&tk_comb, W - 1);
        }
    }

    // ---- termination + backtrack (producer wave; bp published via tk_comb) ----
    if (wv == 0) {
        while (acq(&tk_comb) < NW) __builtin_amdgcn_s_sleep(1);

        float bv = fvv + trans[lane * LBL + EOS];
        int   bi = lane;
#pragma unroll
        for (int d = 1; d < 64; d <<= 1) {
            float ov = __shfl_xor(bv, d, 64);
            int   oi = __shfl_xor(bi, d, 64);
            if (ov > bv || (ov == bv && oi < bi)) { bv = ov; bi = oi; }
        }
        if (lane == 0) out[b] = bv;

        // backtrack: prefetch bp ROWS (tag-independent), chase via readlane
        int stag = bi;
        unsigned char r0 = bp[TT-1][lane];
        unsigned char r1 = bp[TT-2][lane];
        unsigned char r2 = bp[TT-3][lane];
        unsigned char r3 = bp[TT-4][lane];
        for (int t4 = TT - 1; t4 >= 3; t4 -= 4) {
            int q0 = t4-4, q1 = t4-5, q2 = t4-6, q3 = t4-7;
            if (q0 < 0) q0 = 0;  if (q1 < 0) q1 = 0;
            if (q2 < 0) q2 = 0;  if (q3 < 0) q3 = 0;
            unsigned char m0 = bp[q0][lane];
            unsigned char m1 = bp[q1][lane];
            unsigned char m2 = bp[q2][lane];
            unsigned char m3 = bp[q3][lane];
            if (lane == ((t4-0) & 63)) path_s[t4-0] = (unsigned char)stag;
            stag = __builtin_amdgcn_readlane((int)r0, stag);
            if (lane == ((t4-1) & 63)) path_s[t4-1] = (unsigned char)stag;
            stag = __builtin_amdgcn_readlane((int)r1, stag);
            if (lane == ((t4-2) & 63)) path_s[t4-2] = (unsigned char)stag;
            stag = __builtin_amdgcn_readlane((int)r2, stag);
            if (lane == ((t4-3) & 63)) path_s[t4-3] = (unsigned char)stag;
            stag = __builtin_amdgcn_readlane((int)r3, stag);
            r0 = m0; r1 = m1; r2 = m2; r3 = m3;
        }
    }
    __syncthreads();   // path_s visible to all waves (single final barrier)

    // coalesced float path write (all 256 threads)
    float* po = out + BB + (size_t)b * TT;
#pragma unroll
    for (int i = 0; i < TT / 256; ++i)
        po[i * 256 + tid] = (float)path_s[i * 256 + tid];
}

extern "C" void kernel_launch(void* const* d_in, const int* in_sizes, int n_in,
                              void* d_out, int out_size, void* d_ws, size_t ws_size,
                              hipStream_t stream)
{
    const float* X     = (const float*)d_in[0];   // [256, 1024, 64]
    const float* trans = (const float*)d_in[1];   // [64, 64]
    float* out = (float*)d_out;                   // [256] scores ++ [256*1024] path

    viterbi_kernel<<<dim3(BB), dim3(256), 0, stream>>>(X, trans, out);
}

// Round 8
// 440.118 us; speedup vs baseline: 1.4235x; 1.4235x over previous
//
#include <hip/hip_runtime.h>

#define LBL 64
#define TT 1024
#define BB 256
#define BOS 62
#define EOS 63
#define NEGV -10000.0f
#define NW (TT / 8)    // 128 eight-step windows

__device__ __forceinline__ float rl_f(float v, int l) {
    return __uint_as_float(__builtin_amdgcn_readlane(__float_as_uint(v), l));
}

// LDS-only barrier: visibility for ds_write/ds_read WITHOUT draining vmcnt,
// so emission global-loads stay in flight across steps (unlike __syncthreads,
// which emits s_waitcnt vmcnt(0) and stalls ~500-900cyc on the prefetches).
#define LDS_BARRIER() asm volatile("s_waitcnt lgkmcnt(0)\n\ts_barrier" ::: "memory")

// One sentence per block, 4 waves; wave w owns prev-labels [16w,16w+16);
// lane = next-label n. fv replicated in registers in all waves; one
// LDS_BARRIER per step; emissions prefetched one 8-step window ahead.
__global__ __launch_bounds__(256, 1) void viterbi_kernel(
    const float* __restrict__ X, const float* __restrict__ trans,
    float* __restrict__ out)
{
    __shared__ float pval[2][4][LBL];            // 2 KiB partial maxima
    __shared__ unsigned int pidx[2][4][LBL];     // 2 KiB partial arg (0..15)
    __shared__ unsigned char bp[TT][LBL];        // 64 KiB backpointers
    __shared__ unsigned char path_s[TT];

    const int tid  = threadIdx.x;
    const int lane = tid & 63;                   // next-label n
    const int w    = __builtin_amdgcn_readfirstlane(tid >> 6);
    const int b    = blockIdx.x;
    const int wbase = w << 4;

    float tc[16];
#pragma unroll
    for (int i = 0; i < 16; ++i)
        tc[i] = trans[(wbase + i) * LBL + lane];

    const float* Xb = X + (size_t)b * TT * LBL;

    float eA[8], eB[8];
#pragma unroll
    for (int j = 0; j < 8; ++j) eA[j] = Xb[j * LBL + lane];

    float fvv = (lane == BOS) ? 0.0f : NEGV;

    auto STEP = [&](int t, int par, float e) {
        // partial over p in [wbase,wbase+16): 16 readlane+add, tournament argmax
        float sc[16];
#pragma unroll
        for (int i = 0; i < 16; ++i)
            sc[i] = rl_f(fvv, wbase + i) + tc[i];

        float v8[8]; int i8_[8];
#pragma unroll
        for (int k = 0; k < 8; ++k) {
            bool g = sc[2*k+1] > sc[2*k];            // strict '>' + ascending
            v8[k]  = g ? sc[2*k+1] : sc[2*k];        // = first-occurrence
            i8_[k] = g ? (2*k+1)   : (2*k);
        }
        float v4[4]; int i4_[4];
#pragma unroll
        for (int k = 0; k < 4; ++k) {
            bool g = v8[2*k+1] > v8[2*k];
            v4[k]  = g ? v8[2*k+1] : v8[2*k];
            i4_[k] = g ? i8_[2*k+1] : i8_[2*k];
        }
        float v2[2]; int i2_[2];
#pragma unroll
        for (int k = 0; k < 2; ++k) {
            bool g = v4[2*k+1] > v4[2*k];
            v2[k]  = g ? v4[2*k+1] : v4[2*k];
            i2_[k] = g ? i4_[2*k+1] : i4_[2*k];
        }
        {
            bool g = v2[1] > v2[0];
            pval[par][w][lane] = g ? v2[1]  : v2[0];
            pidx[par][w][lane] = (unsigned)(g ? i2_[1] : i2_[0]);
        }

        LDS_BARRIER();   // lgkmcnt only — vmcnt stays outstanding

        float c0 = pval[par][0][lane];
        float c1 = pval[par][1][lane];
        float c2 = pval[par][2][lane];
        float c3 = pval[par][3][lane];
        bool g1 = c1 > c0;  float m01 = g1 ? c1 : c0;
        bool g3 = c3 > c2;  float m23 = g3 ? c3 : c2;
        bool gg = m23 > m01;
        float m = gg ? m23 : m01;                    // 3 maxes on critical path

        if (w == 0) {                                // bp off critical path
            int w01 = g1 ? 1 : 0;
            int w23 = g3 ? 3 : 2;
            int winw = gg ? w23 : w01;
            unsigned li = pidx[par][winw][lane];     // conflict-free gather
            bp[t][lane] = (unsigned char)((winw << 4) + li);
        }
        fvv = m + e;   // exact f32 add — bitwise-identical to numpy
        // slot 'par' rewritten at t+2, after barrier t+1 => race-free
    };

    for (int g2 = 0; g2 < NW; g2 += 2) {
        const int tA = g2 * 8, tB = (g2 + 1) * 8;

        // issue window g2+1's emissions (in flight across the next 8 barriers)
#pragma unroll
        for (int j = 0; j < 8; ++j) {
            int st = tB + j; if (st > TT - 1) st = TT - 1;
            eB[j] = Xb[(size_t)st * LBL + lane];
        }
#pragma unroll
        for (int j = 0; j < 8; ++j) STEP(tA + j, j & 1, eA[j]);

        // issue window g2+2's emissions
#pragma unroll
        for (int j = 0; j < 8; ++j) {
            int st = tB + 8 + j; if (st > TT - 1) st = TT - 1;
            eA[j] = Xb[(size_t)st * LBL + lane];
        }
#pragma unroll
        for (int j = 0; j < 8; ++j) STEP(tB + j, j & 1, eB[j]);
    }

    // ---- termination + backtrack (wave 0; r5/r6-validated readlane chase) ----
    if (w == 0) {
        float bv = fvv + trans[lane * LBL + EOS];
        int   bi = lane;
#pragma unroll
        for (int d = 1; d < 64; d <<= 1) {
            float ov = __shfl_xor(bv, d, 64);
            int   oi = __shfl_xor(bi, d, 64);
            if (ov > bv || (ov == bv && oi < bi)) { bv = ov; bi = oi; }
        }
        if (lane == 0) out[b] = bv;

        int stag = bi;   // wave-uniform
        unsigned char r0 = bp[TT-1][lane];
        unsigned char r1 = bp[TT-2][lane];
        unsigned char r2 = bp[TT-3][lane];
        unsigned char r3 = bp[TT-4][lane];
        for (int t4 = TT - 1; t4 >= 3; t4 -= 4) {
            int q0 = t4-4, q1 = t4-5, q2 = t4-6, q3 = t4-7;
            if (q0 < 0) q0 = 0;  if (q1 < 0) q1 = 0;
            if (q2 < 0) q2 = 0;  if (q3 < 0) q3 = 0;
            unsigned char m0 = bp[q0][lane];
            unsigned char m1 = bp[q1][lane];
            unsigned char m2 = bp[q2][lane];
            unsigned char m3 = bp[q3][lane];
            if (lane == ((t4-0) & 63)) path_s[t4-0] = (unsigned char)stag;
            stag = __builtin_amdgcn_readlane((int)r0, stag);
            if (lane == ((t4-1) & 63)) path_s[t4-1] = (unsigned char)stag;
            stag = __builtin_amdgcn_readlane((int)r1, stag);
            if (lane == ((t4-2) & 63)) path_s[t4-2] = (unsigned char)stag;
            stag = __builtin_amdgcn_readlane((int)r2, stag);
            if (lane == ((t4-3) & 63)) path_s[t4-3] = (unsigned char)stag;
            stag = __builtin_amdgcn_readlane((int)r3, stag);
            r0 = m0; r1 = m1; r2 = m2; r3 = m3;
        }
    }
    __syncthreads();   // full barrier once: path_s visible to all waves

    // coalesced float path write (all 256 threads)
    float* po = out + BB + (size_t)b * TT;
#pragma unroll
    for (int i = 0; i < TT / 256; ++i)
        po[i * 256 + tid] = (float)path_s[i * 256 + tid];
}

extern "C" void kernel_launch(void* const* d_in, const int* in_sizes, int n_in,
                              void* d_out, int out_size, void* d_ws, size_t ws_size,
                              hipStream_t stream)
{
    const float* X     = (const float*)d_in[0];   // [256, 1024, 64]
    const float* trans = (const float*)d_in[1];   // [64, 64]
    float* out = (float*)d_out;                   // [256] scores ++ [256*1024] path

    viterbi_kernel<<<dim3(BB), dim3(256), 0, stream>>>(X, trans, out);
}

// Round 9
// 440.006 us; speedup vs baseline: 1.4239x; 1.0003x over previous
//
#include <hip/hip_runtime.h>

#define LBL 64
#define TT 1024
#define BB 256
#define BOS 62
#define EOS 63
#define NEGV -10000.0f

typedef float v2f __attribute__((ext_vector_type(2)));
typedef float v4f __attribute__((ext_vector_type(4)));

// ONE WAVE per sentence, ZERO barriers. lane = next-label n.
// Value-only fmax reduction (order-independent), argmax recovered exactly
// via equality masks + ctz (first-occurrence == np.argmax). fv row broadcast
// through LDS (same-address b128 reads). No s[64] materialization (r2 lesson).
__global__ __launch_bounds__(64, 1) void viterbi_kernel(
    const float* __restrict__ X, const float* __restrict__ trans,
    float* __restrict__ out)
{
    __shared__ __align__(16) float fvrow[LBL];       // current fv_{t-1} row
    __shared__ __align__(16) float tcT[LBL * LBL];   // [n][p] gather copy, 16 KiB
    __shared__ unsigned char bp[TT][LBL];            // 64 KiB backpointers
    __shared__ unsigned char path_s[TT];

    const int lane = threadIdx.x;            // next-label n
    const int b    = blockIdx.x;

    // tc2[i] = {T[2i][n], T[2i+1][n]} in registers (64 VGPR, pk_add-ready)
    v2f tc2[32];
#pragma unroll
    for (int i = 0; i < 32; ++i) {
        tc2[i].x = trans[(2*i)   * LBL + lane];
        tc2[i].y = trans[(2*i+1) * LBL + lane];
    }
    // LDS copy for the per-lane dynamic gather: tcT[n*64+p] = T[p][n]
#pragma unroll 8
    for (int p = 0; p < LBL; ++p)
        tcT[lane * LBL + p] = trans[p * LBL + lane];

    const float* Xb = X + (size_t)b * TT * LBL;

    float eA[4], eB[4];
#pragma unroll
    for (int j = 0; j < 4; ++j) eA[j] = Xb[j * LBL + lane];

    float fvv = (lane == BOS) ? 0.0f : NEGV;
    fvrow[lane] = fvv;   // single wave: lockstep + LDS program order, no barrier

    auto STEP = [&](int t, float e) {
        // ---- value phase: m = max_p(fv[p] + T[p][n]) ----
        const v4f* fr = (const v4f*)fvrow;   // 16 broadcast ds_read_b128
        float vg[16];
#pragma unroll
        for (int g = 0; g < 16; ++g) {
            v4f f = fr[g];
            v2f a; a.x = f.x; a.y = f.y; a += tc2[2*g];      // v_pk_add_f32
            v2f c; c.x = f.z; c.y = f.w; c += tc2[2*g+1];
            vg[g] = fmaxf(fmaxf(a.x, a.y), fmaxf(c.x, c.y)); // max3-fusable
        }
        float u[8];
#pragma unroll
        for (int k = 0; k < 8; ++k) u[k] = fmaxf(vg[2*k], vg[2*k+1]);
        float q0 = fmaxf(fmaxf(u[0], u[1]), fmaxf(u[2], u[3]));
        float q1 = fmaxf(fmaxf(u[4], u[5]), fmaxf(u[6], u[7]));
        float m  = fmaxf(q0, q1);

        // ---- index phase (exact, off the fv critical path) ----
        // first group with groupmax == m  (ascending bits + ctz = first occurrence)
        unsigned gm = 0u;
#pragma unroll
        for (int g = 0; g < 16; ++g) gm |= (vg[g] == m) ? (1u << g) : 0u;
        const int gs = __builtin_ctz(gm);
        // recompute that group's 4 sums via gather (same ops => bitwise equal)
        v4f f4 = *(const v4f*)&fvrow[4 * gs];
        v4f t4 = *(const v4f*)&tcT[lane * LBL + 4 * gs];
        float s0 = f4.x + t4.x, s1 = f4.y + t4.y;
        float s2 = f4.z + t4.z, s3 = f4.w + t4.w;
        unsigned km = (s0 == m ? 1u : 0u) | (s1 == m ? 2u : 0u)
                    | (s2 == m ? 4u : 0u) | (s3 == m ? 8u : 0u);
        bp[t][lane] = (unsigned char)((gs << 2) | __builtin_ctz(km));

        // ---- advance (reads of fv_{t-1} above precede this overwrite) ----
        fvv = m + e;          // exact f32 add — bitwise-identical to numpy
        fvrow[lane] = fvv;
    };

    for (int w8 = 0; w8 < TT / 4; w8 += 2) {
        const int base = w8 * 4;
#pragma unroll
        for (int j = 0; j < 4; ++j) {          // prefetch window +1 (in flight,
            int st = base + 4 + j;             //  no barriers -> never drained)
            if (st > TT - 1) st = TT - 1;
            eB[j] = Xb[(size_t)st * LBL + lane];
        }
#pragma unroll
        for (int j = 0; j < 4; ++j) STEP(base + j, eA[j]);
#pragma unroll
        for (int j = 0; j < 4; ++j) {          // prefetch window +2
            int st = base + 8 + j;
            if (st > TT - 1) st = TT - 1;
            eA[j] = Xb[(size_t)st * LBL + lane];
        }
#pragma unroll
        for (int j = 0; j < 4; ++j) STEP(base + 4 + j, eB[j]);
    }

    // ---- termination + wave argmax (butterfly, lower index wins ties) ----
    float bv = fvv + trans[lane * LBL + EOS];
    int   bi = lane;
#pragma unroll
    for (int d = 1; d < 64; d <<= 1) {
        float ov = __shfl_xor(bv, d, 64);
        int   oi = __shfl_xor(bi, d, 64);
        if (ov > bv || (ov == bv && oi < bi)) { bv = ov; bi = oi; }
    }
    if (lane == 0) out[b] = bv;

    // ---- backtrack: prefetch bp rows, chase via readlane (r5-validated) ----
    int stag = bi;   // wave-uniform
    unsigned char r0 = bp[TT-1][lane];
    unsigned char r1 = bp[TT-2][lane];
    unsigned char r2 = bp[TT-3][lane];
    unsigned char r3 = bp[TT-4][lane];
    for (int t4 = TT - 1; t4 >= 3; t4 -= 4) {
        int q0 = t4-4, q1 = t4-5, q2 = t4-6, q3 = t4-7;
        if (q0 < 0) q0 = 0;  if (q1 < 0) q1 = 0;
        if (q2 < 0) q2 = 0;  if (q3 < 0) q3 = 0;
        unsigned char m0 = bp[q0][lane];
        unsigned char m1 = bp[q1][lane];
        unsigned char m2 = bp[q2][lane];
        unsigned char m3 = bp[q3][lane];
        if (lane == ((t4-0) & 63)) path_s[t4-0] = (unsigned char)stag;
        stag = __builtin_amdgcn_readlane((int)r0, stag);
        if (lane == ((t4-1) & 63)) path_s[t4-1] = (unsigned char)stag;
        stag = __builtin_amdgcn_readlane((int)r1, stag);
        if (lane == ((t4-2) & 63)) path_s[t4-2] = (unsigned char)stag;
        stag = __builtin_amdgcn_readlane((int)r2, stag);
        if (lane == ((t4-3) & 63)) path_s[t4-3] = (unsigned char)stag;
        stag = __builtin_amdgcn_readlane((int)r3, stag);
        r0 = m0; r1 = m1; r2 = m2; r3 = m3;
    }

    // coalesced float path write (single wave, LDS order within wave)
    float* po = out + BB + (size_t)b * TT;
#pragma unroll
    for (int i = 0; i < TT / LBL; ++i)
        po[i * LBL + lane] = (float)path_s[i * LBL + lane];
}

extern "C" void kernel_launch(void* const* d_in, const int* in_sizes, int n_in,
                              void* d_out, int out_size, void* d_ws, size_t ws_size,
                              hipStream_t stream)
{
    const float* X     = (const float*)d_in[0];   // [256, 1024, 64]
    const float* trans = (const float*)d_in[1];   // [64, 64]
    float* out = (float*)d_out;                   // [256] scores ++ [256*1024] path

    viterbi_kernel<<<dim3(BB), dim3(64), 0, stream>>>(X, trans, out);
}